// Round 1
// baseline (51.518 us; speedup 1.0000x reference)
//
#include <hip/hip_runtime.h>

#define IN_F 4096
#define OUT_F 4096
#define M 32
#define GROUP 128
#define BN 16      // output rows per block (4 waves x TN=4)
#define BK 256     // k sub-chunk staged in LDS
#define TN 4       // output rows per wave/thread

// Main GEMM: grid = (OUT_F/BN) * nsplit blocks of 256 threads.
// Wave owns TN=4 output rows; lanes are k-positions (4 consecutive k each).
// acc[p][q]: q = (m>>1) | (nj<<4), p = m&1  -> reduce-scatter leaves lane l
// owning (nj = l>>4, m = 2*(l&15)+p).
__launch_bounds__(256, 2)
__global__ void qlin_main(const float* __restrict__ x,
                          const int* __restrict__ qw,
                          const float* __restrict__ scales,
                          const float* __restrict__ bias,
                          float* __restrict__ out,
                          float* __restrict__ ws,
                          int nsplit) {
    __shared__ float xs[M][BK];   // 32 KB

    const int t    = threadIdx.x;
    const int lane = t & 63;
    const int wv   = t >> 6;
    const int nblocks = OUT_F / BN;                // 256
    const int nb    = blockIdx.x % nblocks;
    const int split = blockIdx.x / nblocks;
    const int kchunk  = IN_F / nsplit;             // 2048 (nsplit=2) or 4096
    const int k0      = split * kchunk;
    const int nchunks = kchunk / BK;               // 8 or 16

    const int n_base = nb * BN + wv * TN;          // wave's first output row

    float acc[2][64];
#pragma unroll
    for (int p = 0; p < 2; ++p)
#pragma unroll
        for (int q = 0; q < 64; ++q) acc[p][q] = 0.f;

    // x staging map: thread t covers row sm = t/8, cols sk..sk+31
    const int sm = t >> 3;
    const int sk = (t & 7) * 32;
    const int kq = 4 * lane;                        // this lane's k-quad in chunk

    for (int c = 0; c < nchunks; ++c) {
        const int kb = k0 + c * BK;

        // ---- stage x[32][BK] into LDS (coalesced float4, straight layout) ----
#pragma unroll
        for (int i = 0; i < 8; ++i) {
            const float4 v = *reinterpret_cast<const float4*>(&x[sm * IN_F + kb + sk + i * 4]);
            *reinterpret_cast<float4*>(&xs[sm][sk + i * 4]) = v;
        }
        __syncthreads();

        // ---- load + dequant weights: TN rows, 4 consecutive k per lane ----
        float wf[TN][4];
#pragma unroll
        for (int j = 0; j < TN; ++j) {
            const int n = n_base + j;
            const int base = n * IN_F + kb + kq;    // element index, < 2^24
            const int4 w4 = *reinterpret_cast<const int4*>(&qw[base]);
            const float sc = scales[base >> 7];     // 4 k's share one group (aligned)
            wf[j][0] = (float)w4.x * sc;
            wf[j][1] = (float)w4.y * sc;
            wf[j][2] = (float)w4.z * sc;
            wf[j][3] = (float)w4.w * sc;
        }

        // ---- FMA: 32 b128 LDS reads, 512 FMAs per thread ----
#pragma unroll
        for (int m = 0; m < M; ++m) {
            const float4 xv = *reinterpret_cast<const float4*>(&xs[m][kq]);
            const float xvv[4] = {xv.x, xv.y, xv.z, xv.w};
#pragma unroll
            for (int j = 0; j < TN; ++j) {
#pragma unroll
                for (int kk = 0; kk < 4; ++kk)
                    acc[m & 1][(m >> 1) | (j << 4)] += xvv[kk] * wf[j][kk];
            }
        }
        __syncthreads();
    }

    // ---- wave reduce-scatter over the 64 k-lanes (6 stages, compacting) ----
#pragma unroll
    for (int s = 0; s < 6; ++s) {
        const int d = 1 << s;
        const int half = 32 >> s;        // surviving pairs per p this stage
#pragma unroll
        for (int p = 0; p < 2; ++p) {
#pragma unroll
            for (int i = 0; i < 32; ++i) {
                if (i < half) {
                    float a = acc[p][2 * i];
                    float b = acc[p][2 * i + 1];
                    float ta = __shfl_xor(a, d);
                    float tb = __shfl_xor(b, d);
                    acc[p][i] = (lane & d) ? (b + tb) : (a + ta);
                }
            }
        }
    }

    // lane l owns q == l: nj = l>>4, m = 2*(l&15)+p
    const int n = n_base + (lane >> 4);
#pragma unroll
    for (int p = 0; p < 2; ++p) {
        const int m = 2 * (lane & 15) + p;
        const float v = acc[p][0];
        if (nsplit == 1) out[m * OUT_F + n] = v + bias[n];
        else             ws[(split * M + m) * OUT_F + n] = v;
    }
}

__global__ void qlin_reduce(const float* __restrict__ ws,
                            const float* __restrict__ bias,
                            float* __restrict__ out,
                            int nsplit) {
    const int f = blockIdx.x * blockDim.x + threadIdx.x;
    if (f >= M * OUT_F) return;
    float a = bias[f & (OUT_F - 1)];
    for (int s = 0; s < nsplit; ++s) a += ws[s * (M * OUT_F) + f];
    out[f] = a;
}

extern "C" void kernel_launch(void* const* d_in, const int* in_sizes, int n_in,
                              void* d_out, int out_size, void* d_ws, size_t ws_size,
                              hipStream_t stream) {
    const float* x      = (const float*)d_in[0];
    const int*   qw     = (const int*)d_in[1];
    const float* scales = (const float*)d_in[2];
    const float* bias   = (const float*)d_in[3];
    float* out = (float*)d_out;
    float* ws  = (float*)d_ws;

    const size_t need = (size_t)2 * M * OUT_F * sizeof(float);   // 1 MB
    const int nsplit = (ws_size >= need) ? 2 : 1;

    qlin_main<<<dim3((OUT_F / BN) * nsplit), dim3(256), 0, stream>>>(
        x, qw, scales, bias, out, ws, nsplit);
    if (nsplit > 1) {
        qlin_reduce<<<dim3((M * OUT_F + 255) / 256), dim3(256), 0, stream>>>(
            ws, bias, out, nsplit);
    }
}

// Round 2
// 39.000 us; speedup vs baseline: 1.3210x; 1.3210x over previous
//
#include <hip/hip_runtime.h>

#define IN_F 4096
#define OUT_F 4096
#define M 32

// Wave layout: lane = mgroup(2b)*16 + kpos(4b).
//   - 16 k-lanes each own 4 consecutive k (dwordx4) -> 64 k per pass
//   - 4 m-groups each own 8 batch rows (8*4=32 = M)
//   - wave owns TN=4 output rows (n), block = 4 waves -> 16 n-rows
// acc[i*4+j] = partial C[mg*8+i][n_base+j] over this lane's k slices.
// End: 4-stage compacting shfl_xor reduce over the 16 k-lanes; lane ends
// owning flat indices {kpos, 16+kpos} (flat = mloc*4 + j).
template <int NSPLIT>
__launch_bounds__(256, 4)
__global__ void qlin_main(const float* __restrict__ x,
                          const int* __restrict__ qw,
                          const float* __restrict__ scales,
                          const float* __restrict__ bias,
                          float* __restrict__ out,
                          float* __restrict__ ws) {
    const int t    = threadIdx.x;
    const int lane = t & 63;
    const int wv   = t >> 6;
    const int kpos = lane & 15;
    const int mg   = lane >> 4;

    const int nb     = blockIdx.x & 255;      // 256 n-blocks of 16 rows
    const int split  = blockIdx.x >> 8;
    const int n_base = nb * 16 + wv * 4;
    constexpr int KCH    = IN_F / NSPLIT;
    constexpr int PASSES = KCH / 64;
    const int k0   = split * KCH;
    const int kq0  = k0 + 4 * kpos;           // this lane's first k

    float acc[32];
#pragma unroll
    for (int i = 0; i < 32; ++i) acc[i] = 0.f;

    const float* xrow = x + (mg * 8) * IN_F + kq0;

#pragma unroll 2
    for (int p = 0; p < PASSES; ++p) {
        const int kk = kq0 + p * 64;

        // ---- weights: 4 n-rows x 4 k, dequant in regs ----
        float wf[4][4];
#pragma unroll
        for (int j = 0; j < 4; ++j) {
            const int e = (n_base + j) * IN_F + kk;
            const int4 w4 = *reinterpret_cast<const int4*>(qw + e);
            // group index is wave-uniform (64-aligned base, +0..60 never
            // crosses a 128 boundary) -> force scalar load
            const float sc = scales[__builtin_amdgcn_readfirstlane(e >> 7)];
            wf[j][0] = (float)w4.x * sc;
            wf[j][1] = (float)w4.y * sc;
            wf[j][2] = (float)w4.z * sc;
            wf[j][3] = (float)w4.w * sc;
        }

        // ---- x: 8 m-rows x 4 k (L2-resident, no LDS) ----
        float4 xv[8];
#pragma unroll
        for (int i = 0; i < 8; ++i)
            xv[i] = *reinterpret_cast<const float4*>(xrow + i * IN_F + p * 64);

        // ---- 128 FMAs ----
#pragma unroll
        for (int i = 0; i < 8; ++i) {
#pragma unroll
            for (int j = 0; j < 4; ++j) {
                acc[i * 4 + j] += xv[i].x * wf[j][0] + xv[i].y * wf[j][1]
                                + xv[i].z * wf[j][2] + xv[i].w * wf[j][3];
            }
        }
    }

    // ---- compacting butterfly over the 16 k-lanes ----
#pragma unroll
    for (int s = 0; s < 4; ++s) {
        const int d = 1 << s;
        const int cnt = 16 >> s;
#pragma unroll
        for (int i = 0; i < 16; ++i) {
            if (i < cnt) {
                const float a = acc[2 * i], b = acc[2 * i + 1];
                const float ta = __shfl_xor(a, d), tb = __shfl_xor(b, d);
                acc[i] = (kpos & d) ? (b + tb) : (a + ta);
            }
        }
    }

    // lane owns flat {kpos, 16+kpos}; flat = mloc*4 + j
#pragma unroll
    for (int o = 0; o < 2; ++o) {
        const int f = o * 16 + kpos;
        const int m = mg * 8 + (f >> 2);
        const int n = n_base + (f & 3);
        if (NSPLIT == 1) out[m * OUT_F + n] = acc[o] + bias[n];
        else             ws[(split * M + m) * OUT_F + n] = acc[o];
    }
}

__global__ void qlin_reduce(const float* __restrict__ ws,
                            const float* __restrict__ bias,
                            float* __restrict__ out,
                            int nsplit) {
    const int f = blockIdx.x * blockDim.x + threadIdx.x;
    if (f >= M * OUT_F) return;
    float a = bias[f & (OUT_F - 1)];
    for (int s = 0; s < nsplit; ++s) a += ws[s * (M * OUT_F) + f];
    out[f] = a;
}

extern "C" void kernel_launch(void* const* d_in, const int* in_sizes, int n_in,
                              void* d_out, int out_size, void* d_ws, size_t ws_size,
                              hipStream_t stream) {
    const float* x      = (const float*)d_in[0];
    const int*   qw     = (const int*)d_in[1];
    const float* scales = (const float*)d_in[2];
    const float* bias   = (const float*)d_in[3];
    float* out = (float*)d_out;
    float* ws  = (float*)d_ws;

    const size_t part = (size_t)M * OUT_F * sizeof(float);   // 512 KB per split
    if (ws_size >= 4 * part) {
        qlin_main<4><<<dim3(256 * 4), dim3(256), 0, stream>>>(x, qw, scales, bias, out, ws);
        qlin_reduce<<<dim3((M * OUT_F + 255) / 256), dim3(256), 0, stream>>>(ws, bias, out, 4);
    } else if (ws_size >= 2 * part) {
        qlin_main<2><<<dim3(256 * 2), dim3(256), 0, stream>>>(x, qw, scales, bias, out, ws);
        qlin_reduce<<<dim3((M * OUT_F + 255) / 256), dim3(256), 0, stream>>>(ws, bias, out, 2);
    } else {
        qlin_main<1><<<dim3(256), dim3(256), 0, stream>>>(x, qw, scales, bias, out, ws);
    }
}

// Round 3
// 29.164 us; speedup vs baseline: 1.7665x; 1.3373x over previous
//
#include <hip/hip_runtime.h>

typedef __bf16 bf16x8 __attribute__((ext_vector_type(8)));
typedef float f32x4 __attribute__((ext_vector_type(4)));

#define IN_F 4096
#define OUT_F 4096
#define M 32

// One block (8 waves) per 16-row n-tile; wave wv owns k in [wv*512, wv*512+512).
// Swapped MFMA: D[n][m] = W_tile(16x32) x X^T(32x16), 16x16x32 bf16.
// A-frag lane l: W[n0 + (l&15)][k = step*32 + (l>>4)*8 + j]  (8 consecutive int32)
// B-frag lane l: X[h*16 + (l&15)][same k]                    (8 consecutive fp32)
// D lane l reg r: n_loc = (l>>4)*4 + r, m_loc = l&15   (verified layout)
__launch_bounds__(512, 2)
__global__ void qlin_mfma(const float* __restrict__ x,
                          const int* __restrict__ qw,
                          const float* __restrict__ scales,
                          const float* __restrict__ bias,
                          float* __restrict__ out) {
    __shared__ float red[8][2][16][20];   // [wave][mtile][m_loc][n_loc pad20] = 20 KB

    const int t    = threadIdx.x;
    const int lane = t & 63;
    const int wv   = t >> 6;            // 0..7
    const int l16  = lane & 15;
    const int g    = lane >> 4;         // 0..3

    const int n0  = blockIdx.x * 16;
    const int row = n0 + l16;           // weight row this lane dequants
    const int kw0 = wv * 512;           // wave's k base

    const int*   wp  = qw + row * IN_F + kw0 + g * 8;
    const float* xp0 = x  + (l16)      * IN_F + kw0 + g * 8;   // m-tile 0
    const float* xp1 = x  + (16 + l16) * IN_F + kw0 + g * 8;   // m-tile 1
    const int scbase = row * (IN_F / 128) + (kw0 >> 7);

    f32x4 acc0 = {0.f, 0.f, 0.f, 0.f};
    f32x4 acc1 = {0.f, 0.f, 0.f, 0.f};

    struct Raw { int4 w0, w1; float sc; float4 xa0, xa1, xb0, xb1; };

    auto load_step = [&](int s) {
        Raw r;
        const int off = s * 32;
        r.w0  = *reinterpret_cast<const int4*>(wp + off);
        r.w1  = *reinterpret_cast<const int4*>(wp + off + 4);
        r.sc  = scales[scbase + (s >> 2)];          // 8-aligned k never crosses a group
        r.xa0 = *reinterpret_cast<const float4*>(xp0 + off);
        r.xa1 = *reinterpret_cast<const float4*>(xp0 + off + 4);
        r.xb0 = *reinterpret_cast<const float4*>(xp1 + off);
        r.xb1 = *reinterpret_cast<const float4*>(xp1 + off + 4);
        return r;
    };

    auto compute = [&](const Raw& r) {
        bf16x8 af, b0, b1;
        af[0] = (__bf16)((float)r.w0.x * r.sc);
        af[1] = (__bf16)((float)r.w0.y * r.sc);
        af[2] = (__bf16)((float)r.w0.z * r.sc);
        af[3] = (__bf16)((float)r.w0.w * r.sc);
        af[4] = (__bf16)((float)r.w1.x * r.sc);
        af[5] = (__bf16)((float)r.w1.y * r.sc);
        af[6] = (__bf16)((float)r.w1.z * r.sc);
        af[7] = (__bf16)((float)r.w1.w * r.sc);
        b0[0] = (__bf16)r.xa0.x;  b0[1] = (__bf16)r.xa0.y;
        b0[2] = (__bf16)r.xa0.z;  b0[3] = (__bf16)r.xa0.w;
        b0[4] = (__bf16)r.xa1.x;  b0[5] = (__bf16)r.xa1.y;
        b0[6] = (__bf16)r.xa1.z;  b0[7] = (__bf16)r.xa1.w;
        b1[0] = (__bf16)r.xb0.x;  b1[1] = (__bf16)r.xb0.y;
        b1[2] = (__bf16)r.xb0.z;  b1[3] = (__bf16)r.xb0.w;
        b1[4] = (__bf16)r.xb1.x;  b1[5] = (__bf16)r.xb1.y;
        b1[6] = (__bf16)r.xb1.z;  b1[7] = (__bf16)r.xb1.w;
        acc0 = __builtin_amdgcn_mfma_f32_16x16x32_bf16(af, b0, acc0, 0, 0, 0);
        acc1 = __builtin_amdgcn_mfma_f32_16x16x32_bf16(af, b1, acc1, 0, 0, 0);
    };

    // depth-2 register prefetch, fully unrolled (all indices static)
    Raw cur = load_step(0);
#pragma unroll
    for (int s = 0; s < 15; ++s) {
        Raw nxt = load_step(s + 1);
        compute(cur);
        cur = nxt;
    }
    compute(cur);

    // ---- cross-wave reduce in LDS ----
    *reinterpret_cast<f32x4*>(&red[wv][0][l16][g * 4]) = acc0;  // 80B rows: 16B-aligned
    *reinterpret_cast<f32x4*>(&red[wv][1][l16][g * 4]) = acc1;
    __syncthreads();

    const int h  = t >> 8;          // m-tile
    const int rm = t & 255;
    const int ml = rm >> 4;
    const int nl = rm & 15;
    float sum = bias[n0 + nl];
#pragma unroll
    for (int w = 0; w < 8; ++w) sum += red[w][h][ml][nl];
    out[(h * 16 + ml) * OUT_F + n0 + nl] = sum;
}

extern "C" void kernel_launch(void* const* d_in, const int* in_sizes, int n_in,
                              void* d_out, int out_size, void* d_ws, size_t ws_size,
                              hipStream_t stream) {
    const float* x      = (const float*)d_in[0];
    const int*   qw     = (const int*)d_in[1];
    const float* scales = (const float*)d_in[2];
    const float* bias   = (const float*)d_in[3];
    float* out = (float*)d_out;

    qlin_mfma<<<dim3(OUT_F / 16), dim3(512), 0, stream>>>(x, qw, scales, bias, out);
}

// Round 4
// 28.731 us; speedup vs baseline: 1.7931x; 1.0151x over previous
//
#include <hip/hip_runtime.h>

typedef __bf16 bf16x8 __attribute__((ext_vector_type(8)));
typedef float f32x4 __attribute__((ext_vector_type(4)));

#define IN_F 4096
#define OUT_F 4096
#define M 32

// ---- x fp32 -> bf16, into d_ws (256 KB). 131072 elems, 8 per thread. ----
__global__ __launch_bounds__(256) void xconv(const float* __restrict__ x,
                                             __bf16* __restrict__ xb) {
    const int i = (blockIdx.x * 256 + threadIdx.x) * 8;
    const float4 a = *reinterpret_cast<const float4*>(x + i);
    const float4 b = *reinterpret_cast<const float4*>(x + i + 4);
    bf16x8 v;
    v[0] = (__bf16)a.x; v[1] = (__bf16)a.y; v[2] = (__bf16)a.z; v[3] = (__bf16)a.w;
    v[4] = (__bf16)b.x; v[5] = (__bf16)b.y; v[6] = (__bf16)b.z; v[7] = (__bf16)b.w;
    *reinterpret_cast<bf16x8*>(xb + i) = v;
}

// ---- main: one 1024-thread block per 16-row n-tile (grid=256, 1 block/CU).
// 16 waves; wave wv owns k in [wv*256, wv*256+256) = 8 steps of 32 k.
// Swapped MFMA 16x16x32 bf16: A = dequant W rows (n), B = x^T (m).
// A/B use the same lane->(row, k) map; D: n_loc=(l>>4)*4+reg, m_loc=l&15
// (verified: round-3 passed absmax 0.125).
__launch_bounds__(1024, 4)
__global__ void qlin_mfma(const __bf16* __restrict__ xb,
                          const int* __restrict__ qw,
                          const float* __restrict__ scales,
                          const float* __restrict__ bias,
                          float* __restrict__ out) {
    __shared__ float red[16][2][16][20];   // [wave][mtile][m_loc][n_loc pad] = 40 KB

    const int t    = threadIdx.x;
    const int lane = t & 63;
    const int wv   = t >> 6;            // 0..15
    const int l16  = lane & 15;
    const int g    = lane >> 4;         // 0..3

    const int n0  = blockIdx.x * 16;
    const int row = n0 + l16;
    const int kw0 = wv * 256;

    const int*    wp  = qw + row * IN_F + kw0 + g * 8;
    const __bf16* xpa = xb + l16 * IN_F + kw0 + g * 8;         // m-tile 0
    const __bf16* xpb = xb + (16 + l16) * IN_F + kw0 + g * 8;  // m-tile 1
    const int scbase  = row * (IN_F / 128) + (kw0 >> 7);

    f32x4 acc0 = {0.f, 0.f, 0.f, 0.f};
    f32x4 acc1 = {0.f, 0.f, 0.f, 0.f};

    struct Raw { int4 w0, w1; float sc; bf16x8 b0, b1; };

    auto load_step = [&](int s) {
        Raw r;
        const int off = s * 32;                    // 8-aligned k: group-safe
        r.w0 = *reinterpret_cast<const int4*>(wp + off);
        r.w1 = *reinterpret_cast<const int4*>(wp + off + 4);
        r.sc = scales[scbase + (s >> 2)];
        r.b0 = *reinterpret_cast<const bf16x8*>(xpa + off);
        r.b1 = *reinterpret_cast<const bf16x8*>(xpb + off);
        return r;
    };

    auto compute = [&](const Raw& r) {
        bf16x8 af;
        af[0] = (__bf16)((float)r.w0.x * r.sc);
        af[1] = (__bf16)((float)r.w0.y * r.sc);
        af[2] = (__bf16)((float)r.w0.z * r.sc);
        af[3] = (__bf16)((float)r.w0.w * r.sc);
        af[4] = (__bf16)((float)r.w1.x * r.sc);
        af[5] = (__bf16)((float)r.w1.y * r.sc);
        af[6] = (__bf16)((float)r.w1.z * r.sc);
        af[7] = (__bf16)((float)r.w1.w * r.sc);
        acc0 = __builtin_amdgcn_mfma_f32_16x16x32_bf16(af, r.b0, acc0, 0, 0, 0);
        acc1 = __builtin_amdgcn_mfma_f32_16x16x32_bf16(af, r.b1, acc1, 0, 0, 0);
    };

    // depth-3 register pipeline, fully static after unroll
    Raw c0 = load_step(0);
    Raw c1 = load_step(1);
#pragma unroll
    for (int s = 0; s < 6; ++s) {
        Raw c2 = load_step(s + 2);
        compute(c0);
        c0 = c1;
        c1 = c2;
    }
    compute(c0);
    compute(c1);

    // ---- cross-wave reduce in LDS ----
    *reinterpret_cast<f32x4*>(&red[wv][0][l16][g * 4]) = acc0;
    *reinterpret_cast<f32x4*>(&red[wv][1][l16][g * 4]) = acc1;
    __syncthreads();

    if (t < 512) {
        const int h  = t >> 8;          // m-tile
        const int ml = (t >> 4) & 15;   // m_loc
        const int nl = t & 15;          // n_loc
        float sum = bias[n0 + nl];
#pragma unroll
        for (int w = 0; w < 16; ++w) sum += red[w][h][ml][nl];
        out[(h * 16 + ml) * OUT_F + n0 + nl] = sum;
    }
}

extern "C" void kernel_launch(void* const* d_in, const int* in_sizes, int n_in,
                              void* d_out, int out_size, void* d_ws, size_t ws_size,
                              hipStream_t stream) {
    const float* x      = (const float*)d_in[0];
    const int*   qw     = (const int*)d_in[1];
    const float* scales = (const float*)d_in[2];
    const float* bias   = (const float*)d_in[3];
    float* out  = (float*)d_out;
    __bf16* xbw = (__bf16*)d_ws;    // 256 KB of ws

    xconv<<<dim3((M * IN_F) / (256 * 8)), dim3(256), 0, stream>>>(x, xbw);
    qlin_mfma<<<dim3(OUT_F / 16), dim3(1024), 0, stream>>>(xbw, qw, scales, bias, out);
}

// Round 5
// 25.788 us; speedup vs baseline: 1.9977x; 1.1141x over previous
//
#include <hip/hip_runtime.h>

typedef __bf16 bf16x8 __attribute__((ext_vector_type(8)));
typedef float f32x4 __attribute__((ext_vector_type(4)));

#define IN_F 4096
#define OUT_F 4096
#define M 32
#define BN 128          // n-rows per block
#define KC 512          // k-chunk per block
#define KSTEP 64
#define NSPLIT 8        // IN_F / KC
#define NTILE 32        // OUT_F / BN

// async global->LDS, 16B per lane, LDS dest = wave-uniform base + lane*16
__device__ __forceinline__ void gload16(const void* g, void* l) {
    __builtin_amdgcn_global_load_lds(
        (const __attribute__((address_space(1))) void*)g,
        (__attribute__((address_space(3))) void*)l, 16, 0, 0);
}

// ---- x fp32 -> bf16 into ws ----
__global__ __launch_bounds__(256) void xconv(const float* __restrict__ x,
                                             __bf16* __restrict__ xb) {
    const int i = (blockIdx.x * 256 + threadIdx.x) * 8;
    const float4 a = *reinterpret_cast<const float4*>(x + i);
    const float4 b = *reinterpret_cast<const float4*>(x + i + 4);
    bf16x8 v;
    v[0] = (__bf16)a.x; v[1] = (__bf16)a.y; v[2] = (__bf16)a.z; v[3] = (__bf16)a.w;
    v[4] = (__bf16)b.x; v[5] = (__bf16)b.y; v[6] = (__bf16)b.z; v[7] = (__bf16)b.w;
    *reinterpret_cast<bf16x8*>(xb + i) = v;
}

// ---- main GEMM: 256 blocks = 32 n-tiles x 8 k-splits, 512 thr = 8 waves.
// Wave wv owns n-rows [n0+wv*16, +16) and BOTH m-halves (acc0: m0-15, acc1: m16-31).
// W and x staged per K-step via global_load_lds (linear LDS, pre-swizzled global
// source: slot ^= row&7); ds_read_b128 frags with matching XOR -> 2-way max.
__launch_bounds__(512, 2)
__global__ void qlin_gemm(const __bf16* __restrict__ xb,
                          const int* __restrict__ qw,
                          const float* __restrict__ scales,
                          float* __restrict__ part) {
    __shared__ int    Wb[2][BN][KSTEP];     // 2 x 32 KB
    __shared__ __bf16 Xb[2][M][KSTEP];      // 2 x 4 KB

    const int t    = threadIdx.x;
    const int lane = t & 63;
    const int wv   = t >> 6;      // 0..7
    const int l16  = lane & 15;
    const int g4   = lane >> 4;   // 0..3

    const int nt    = blockIdx.x & (NTILE - 1);
    const int split = blockIdx.x >> 5;
    const int n0    = nt * BN;
    const int k0    = split * KC;

    // per-lane persistent scales: this wave's A-row, 4 groups of this split
    const int arow = n0 + wv * 16 + l16;
    const f32x4 sc = *reinterpret_cast<const f32x4*>(
        scales + arow * (IN_F / 128) + split * 4);

    f32x4 a0 = {0.f, 0.f, 0.f, 0.f};
    f32x4 a1 = {0.f, 0.f, 0.f, 0.f};

    auto stage = [&](int buf, int s) {
        const int kk = k0 + s * KSTEP;
        // W: wave stages LDS rows [wv*16, +16), 4 rows per instr (4 x 256 B)
#pragma unroll
        for (int i = 0; i < 4; ++i) {
            const int r    = wv * 16 + i * 4 + g4;      // LDS row == tile row
            const int slot = l16 ^ (r & 7);             // pre-swizzled source
            gload16(qw + (size_t)(n0 + r) * IN_F + kk + slot * 4,
                    &Wb[buf][wv * 16 + i * 4][0]);
        }
        // x: waves 0..3 stage 8 rows each (8 x 128 B per instr)
        if (wv < 4) {
            const int r    = wv * 8 + (lane >> 3);
            const int slot = (lane & 7) ^ (r & 7);
            gload16(xb + (size_t)r * IN_F + kk + slot * 8,
                    &Xb[buf][wv * 8][0]);
        }
    };

    auto compute = [&](int buf, int s) {
#pragma unroll
        for (int q = 0; q < 2; ++q) {
            const int gidx = (s * 2 + q) >> 2;          // static after unroll
            const int r    = wv * 16 + l16;             // A row; r&7 == l16&7
            const int s0   = q * 8 + g4 * 2;            // linear 16B slot
            const int4 w0 = *reinterpret_cast<const int4*>(
                &Wb[buf][r][((s0)     ^ (l16 & 7)) * 4]);
            const int4 w1 = *reinterpret_cast<const int4*>(
                &Wb[buf][r][((s0 + 1) ^ (l16 & 7)) * 4]);
            const float fs = sc[gidx];
            bf16x8 af;
            af[0] = (__bf16)((float)w0.x * fs);
            af[1] = (__bf16)((float)w0.y * fs);
            af[2] = (__bf16)((float)w0.z * fs);
            af[3] = (__bf16)((float)w0.w * fs);
            af[4] = (__bf16)((float)w1.x * fs);
            af[5] = (__bf16)((float)w1.y * fs);
            af[6] = (__bf16)((float)w1.z * fs);
            af[7] = (__bf16)((float)w1.w * fs);
            const int sb = ((q * 4 + g4) ^ (l16 & 7)) * 8;   // (16+l16)&7 == l16&7
            const bf16x8 b0 = *reinterpret_cast<const bf16x8*>(&Xb[buf][l16][sb]);
            const bf16x8 b1 = *reinterpret_cast<const bf16x8*>(&Xb[buf][16 + l16][sb]);
            a0 = __builtin_amdgcn_mfma_f32_16x16x32_bf16(af, b0, a0, 0, 0, 0);
            a1 = __builtin_amdgcn_mfma_f32_16x16x32_bf16(af, b1, a1, 0, 0, 0);
        }
    };

    stage(0, 0);
    __syncthreads();
#pragma unroll
    for (int s = 0; s < 8; ++s) {
        if (s < 7) stage((s + 1) & 1, s + 1);   // flies under compute(s)
        compute(s & 1, s);
        if (s < 7) __syncthreads();             // drains stage(s+1) + ds reads
    }

    // D layout (verified): m = l16 (+16 for a1), n = n0 + wv*16 + g4*4 + r
    float* dst = part + (size_t)split * (M * OUT_F);
    const int nb = n0 + wv * 16 + g4 * 4;
    *reinterpret_cast<f32x4*>(dst + (size_t)l16 * OUT_F + nb)        = a0;
    *reinterpret_cast<f32x4*>(dst + (size_t)(16 + l16) * OUT_F + nb) = a1;
}

// ---- partials + bias -> out ----
__global__ __launch_bounds__(256) void qlin_reduce(const float* __restrict__ part,
                                                   const float* __restrict__ bias,
                                                   float* __restrict__ out) {
    const int i = (blockIdx.x * 256 + threadIdx.x) * 4;
    const int n = i & (OUT_F - 1);
    f32x4 s = *reinterpret_cast<const f32x4*>(bias + n);
#pragma unroll
    for (int p = 0; p < NSPLIT; ++p)
        s += *reinterpret_cast<const f32x4*>(part + (size_t)p * (M * OUT_F) + i);
    *reinterpret_cast<f32x4*>(out + i) = s;
}

// ---- fallback (round-3 validated, no ws needed) ----
__launch_bounds__(512, 2)
__global__ void qlin_fallback(const float* __restrict__ x,
                              const int* __restrict__ qw,
                              const float* __restrict__ scales,
                              const float* __restrict__ bias,
                              float* __restrict__ out) {
    __shared__ float red[8][2][16][20];
    const int t = threadIdx.x, lane = t & 63, wv = t >> 6;
    const int l16 = lane & 15, g = lane >> 4;
    const int n0 = blockIdx.x * 16, row = n0 + l16, kw0 = wv * 512;
    const int*   wp  = qw + row * IN_F + kw0 + g * 8;
    const float* xp0 = x + l16 * IN_F + kw0 + g * 8;
    const float* xp1 = x + (16 + l16) * IN_F + kw0 + g * 8;
    const int scbase = row * (IN_F / 128) + (kw0 >> 7);
    f32x4 acc0 = {0.f,0.f,0.f,0.f}, acc1 = {0.f,0.f,0.f,0.f};
#pragma unroll
    for (int s = 0; s < 16; ++s) {
        const int off = s * 32;
        const int4 w0 = *reinterpret_cast<const int4*>(wp + off);
        const int4 w1 = *reinterpret_cast<const int4*>(wp + off + 4);
        const float scv = scales[scbase + (s >> 2)];
        const float4 xa0 = *reinterpret_cast<const float4*>(xp0 + off);
        const float4 xa1 = *reinterpret_cast<const float4*>(xp0 + off + 4);
        const float4 xb0 = *reinterpret_cast<const float4*>(xp1 + off);
        const float4 xb1 = *reinterpret_cast<const float4*>(xp1 + off + 4);
        bf16x8 af, b0, b1;
        af[0]=(__bf16)((float)w0.x*scv); af[1]=(__bf16)((float)w0.y*scv);
        af[2]=(__bf16)((float)w0.z*scv); af[3]=(__bf16)((float)w0.w*scv);
        af[4]=(__bf16)((float)w1.x*scv); af[5]=(__bf16)((float)w1.y*scv);
        af[6]=(__bf16)((float)w1.z*scv); af[7]=(__bf16)((float)w1.w*scv);
        b0[0]=(__bf16)xa0.x; b0[1]=(__bf16)xa0.y; b0[2]=(__bf16)xa0.z; b0[3]=(__bf16)xa0.w;
        b0[4]=(__bf16)xa1.x; b0[5]=(__bf16)xa1.y; b0[6]=(__bf16)xa1.z; b0[7]=(__bf16)xa1.w;
        b1[0]=(__bf16)xb0.x; b1[1]=(__bf16)xb0.y; b1[2]=(__bf16)xb0.z; b1[3]=(__bf16)xb0.w;
        b1[4]=(__bf16)xb1.x; b1[5]=(__bf16)xb1.y; b1[6]=(__bf16)xb1.z; b1[7]=(__bf16)xb1.w;
        acc0 = __builtin_amdgcn_mfma_f32_16x16x32_bf16(af, b0, acc0, 0,0,0);
        acc1 = __builtin_amdgcn_mfma_f32_16x16x32_bf16(af, b1, acc1, 0,0,0);
    }
    *reinterpret_cast<f32x4*>(&red[wv][0][l16][g*4]) = acc0;
    *reinterpret_cast<f32x4*>(&red[wv][1][l16][g*4]) = acc1;
    __syncthreads();
    const int h = t >> 8, ml = (t >> 4) & 15, nl = t & 15;
    float sum = bias[n0 + nl];
#pragma unroll
    for (int w = 0; w < 8; ++w) sum += red[w][h & 1][ml][nl];
    if (t < 512) out[(h * 16 + ml) * OUT_F + n0 + nl] = sum;
}

extern "C" void kernel_launch(void* const* d_in, const int* in_sizes, int n_in,
                              void* d_out, int out_size, void* d_ws, size_t ws_size,
                              hipStream_t stream) {
    const float* x      = (const float*)d_in[0];
    const int*   qw     = (const int*)d_in[1];
    const float* scales = (const float*)d_in[2];
    const float* bias   = (const float*)d_in[3];
    float* out = (float*)d_out;

    const size_t NEED = 262144 + (size_t)NSPLIT * M * OUT_F * 4;   // 4.5 MB
    if (ws_size >= NEED) {
        __bf16* xbw  = (__bf16*)d_ws;
        float*  part = (float*)d_ws + 65536;        // after 256 KB of xb
        xconv<<<dim3((M * IN_F) / (256 * 8)), dim3(256), 0, stream>>>(x, xbw);
        qlin_gemm<<<dim3(NTILE * NSPLIT), dim3(512), 0, stream>>>(xbw, qw, scales, part);
        qlin_reduce<<<dim3((M * OUT_F) / (256 * 4)), dim3(256), 0, stream>>>(part, bias, out);
    } else {
        qlin_fallback<<<dim3(OUT_F / 16), dim3(512), 0, stream>>>(x, qw, scales, bias, out);
    }
}

// Round 6
// 21.099 us; speedup vs baseline: 2.4417x; 1.2222x over previous
//
#include <hip/hip_runtime.h>

typedef __bf16 bf16x8 __attribute__((ext_vector_type(8)));
typedef float f32x4 __attribute__((ext_vector_type(4)));

#define IN_F 4096
#define OUT_F 4096
#define M 32
#define BN 64           // n-rows per block
#define KC 512          // k-chunk per block
#define KSTEP 64
#define STEPS 8         // KC / KSTEP
#define NSPLIT 8        // IN_F / KC
#define NTILE 64        // OUT_F / BN

// async global->LDS, 16B/lane, LDS dest = wave-uniform base + lane*16
__device__ __forceinline__ void gload16(const void* g, void* l) {
    __builtin_amdgcn_global_load_lds(
        (const __attribute__((address_space(1))) void*)g,
        (__attribute__((address_space(3))) void*)l, 16, 0, 0);
}

// ---- main GEMM: 512 blocks = 64 n-tiles x 8 k-splits, 256 thr = 4 waves.
// LDS 64 KB -> exactly 2 blocks/CU. Wave wv owns n-rows [n0+wv*16,+16),
// both m-halves. X converted fp32->bf16 in-kernel, staged ONCE (swizzled
// reg-staged ds_write). W double-buffered per K-step via global_load_lds
// (linear LDS dest, XOR-preswizzled global source; matching XOR on read).
__launch_bounds__(256, 2)
__global__ void qlin_gemm(const float* __restrict__ x,
                          const int* __restrict__ qw,
                          const float* __restrict__ scales,
                          float* __restrict__ part) {
    __shared__ int    Wb[2][BN][KSTEP];   // 2 x 16 KB
    __shared__ __bf16 Xs[M][KC];          // 32 KB

    const int t    = threadIdx.x;
    const int lane = t & 63;
    const int wv   = t >> 6;      // 0..3
    const int l16  = lane & 15;
    const int g4   = lane >> 4;   // 0..3
    const int xr   = l16 & 7;

    const int nt    = blockIdx.x & (NTILE - 1);
    const int split = blockIdx.x >> 6;
    const int n0    = nt * BN;
    const int k0    = split * KC;

    // per-lane persistent scales: wave's A-row, the 4 groups of this split
    const int arow = n0 + wv * 16 + l16;
    const f32x4 sc = *reinterpret_cast<const f32x4*>(
        scales + arow * (IN_F / 128) + split * 4);

    f32x4 a0 = {0.f, 0.f, 0.f, 0.f};
    f32x4 a1 = {0.f, 0.f, 0.f, 0.f};

    auto stageW = [&](int buf, int s) {
        const int kk = k0 + s * KSTEP;
#pragma unroll
        for (int i = 0; i < 4; ++i) {
            const int r    = wv * 16 + i * 4 + g4;   // LDS row == tile row
            const int slot = l16 ^ (r & 7);          // involution, bit3 kept
            gload16(qw + (size_t)(n0 + r) * IN_F + kk + slot * 4,
                    &Wb[buf][wv * 16 + i * 4][0]);
        }
    };

    // ---- prologue: convert+stage X once (reg-staged, swizzled ds_write),
    //      stage W step 0; one barrier drains everything ----
#pragma unroll
    for (int i = 0; i < 8; ++i) {
        const int r = wv * 8 + i;
        const float4 a = *reinterpret_cast<const float4*>(
            x + (size_t)r * IN_F + k0 + lane * 8);
        const float4 b = *reinterpret_cast<const float4*>(
            x + (size_t)r * IN_F + k0 + lane * 8 + 4);
        bf16x8 v;
        v[0] = (__bf16)a.x; v[1] = (__bf16)a.y; v[2] = (__bf16)a.z; v[3] = (__bf16)a.w;
        v[4] = (__bf16)b.x; v[5] = (__bf16)b.y; v[6] = (__bf16)b.z; v[7] = (__bf16)b.w;
        const int c = (lane & ~7) | ((lane & 7) ^ (r & 7));
        *reinterpret_cast<bf16x8*>(&Xs[r][c * 8]) = v;
    }
    stageW(0, 0);
    __syncthreads();

    auto compute = [&](int buf, int s) {
#pragma unroll
        for (int q = 0; q < 2; ++q) {
            const int s0 = q * 8 + g4 * 2;
            const int4 w0 = *reinterpret_cast<const int4*>(
                &Wb[buf][wv * 16 + l16][((s0)     ^ xr) * 4]);
            const int4 w1 = *reinterpret_cast<const int4*>(
                &Wb[buf][wv * 16 + l16][((s0 + 1) ^ xr) * 4]);
            const float fs = sc[(2 * s + q) >> 2];   // static after unroll
            bf16x8 af;
            af[0] = (__bf16)((float)w0.x * fs);
            af[1] = (__bf16)((float)w0.y * fs);
            af[2] = (__bf16)((float)w0.z * fs);
            af[3] = (__bf16)((float)w0.w * fs);
            af[4] = (__bf16)((float)w1.x * fs);
            af[5] = (__bf16)((float)w1.y * fs);
            af[6] = (__bf16)((float)w1.z * fs);
            af[7] = (__bf16)((float)w1.w * fs);
            const int xc = (s * 8) | ((q * 4 + g4) ^ xr);
            const bf16x8 b0 = *reinterpret_cast<const bf16x8*>(&Xs[l16][xc * 8]);
            const bf16x8 b1 = *reinterpret_cast<const bf16x8*>(&Xs[16 + l16][xc * 8]);
            a0 = __builtin_amdgcn_mfma_f32_16x16x32_bf16(af, b0, a0, 0, 0, 0);
            a1 = __builtin_amdgcn_mfma_f32_16x16x32_bf16(af, b1, a1, 0, 0, 0);
        }
    };

#pragma unroll
    for (int s = 0; s < STEPS; ++s) {
        if (s < STEPS - 1) stageW((s + 1) & 1, s + 1);   // flies under compute(s)
        compute(s & 1, s);
        if (s < STEPS - 1) __syncthreads();   // drains stage(s+1); guards buf reuse
    }

    // D layout (verified R3/R5): m = l16 (+16 for a1), n = n0 + wv*16 + g4*4 + reg
    float* dst = part + (size_t)split * (M * OUT_F);
    const int nb = n0 + wv * 16 + g4 * 4;
    *reinterpret_cast<f32x4*>(dst + (size_t)l16 * OUT_F + nb)        = a0;
    *reinterpret_cast<f32x4*>(dst + (size_t)(16 + l16) * OUT_F + nb) = a1;
}

// ---- partials + bias -> out ----
__global__ __launch_bounds__(256) void qlin_reduce(const float* __restrict__ part,
                                                   const float* __restrict__ bias,
                                                   float* __restrict__ out) {
    const int i = (blockIdx.x * 256 + threadIdx.x) * 4;
    const int n = i & (OUT_F - 1);
    f32x4 s = *reinterpret_cast<const f32x4*>(bias + n);
#pragma unroll
    for (int p = 0; p < NSPLIT; ++p)
        s += *reinterpret_cast<const f32x4*>(part + (size_t)p * (M * OUT_F) + i);
    *reinterpret_cast<f32x4*>(out + i) = s;
}

// ---- fallback (round-3 validated, no ws needed) ----
__launch_bounds__(512, 2)
__global__ void qlin_fallback(const float* __restrict__ x,
                              const int* __restrict__ qw,
                              const float* __restrict__ scales,
                              const float* __restrict__ bias,
                              float* __restrict__ out) {
    __shared__ float red[8][2][16][20];
    const int t = threadIdx.x, lane = t & 63, wv = t >> 6;
    const int l16 = lane & 15, g = lane >> 4;
    const int n0 = blockIdx.x * 16, row = n0 + l16, kw0 = wv * 512;
    const int*   wp  = qw + row * IN_F + kw0 + g * 8;
    const float* xp0 = x + l16 * IN_F + kw0 + g * 8;
    const float* xp1 = x + (16 + l16) * IN_F + kw0 + g * 8;
    const int scbase = row * (IN_F / 128) + (kw0 >> 7);
    f32x4 acc0 = {0.f,0.f,0.f,0.f}, acc1 = {0.f,0.f,0.f,0.f};
#pragma unroll
    for (int s = 0; s < 16; ++s) {
        const int off = s * 32;
        const int4 w0 = *reinterpret_cast<const int4*>(wp + off);
        const int4 w1 = *reinterpret_cast<const int4*>(wp + off + 4);
        const float scv = scales[scbase + (s >> 2)];
        const float4 xa0 = *reinterpret_cast<const float4*>(xp0 + off);
        const float4 xa1 = *reinterpret_cast<const float4*>(xp0 + off + 4);
        const float4 xb0 = *reinterpret_cast<const float4*>(xp1 + off);
        const float4 xb1 = *reinterpret_cast<const float4*>(xp1 + off + 4);
        bf16x8 af, b0, b1;
        af[0]=(__bf16)((float)w0.x*scv); af[1]=(__bf16)((float)w0.y*scv);
        af[2]=(__bf16)((float)w0.z*scv); af[3]=(__bf16)((float)w0.w*scv);
        af[4]=(__bf16)((float)w1.x*scv); af[5]=(__bf16)((float)w1.y*scv);
        af[6]=(__bf16)((float)w1.z*scv); af[7]=(__bf16)((float)w1.w*scv);
        b0[0]=(__bf16)xa0.x; b0[1]=(__bf16)xa0.y; b0[2]=(__bf16)xa0.z; b0[3]=(__bf16)xa0.w;
        b0[4]=(__bf16)xa1.x; b0[5]=(__bf16)xa1.y; b0[6]=(__bf16)xa1.z; b0[7]=(__bf16)xa1.w;
        b1[0]=(__bf16)xb0.x; b1[1]=(__bf16)xb0.y; b1[2]=(__bf16)xb0.z; b1[3]=(__bf16)xb0.w;
        b1[4]=(__bf16)xb1.x; b1[5]=(__bf16)xb1.y; b1[6]=(__bf16)xb1.z; b1[7]=(__bf16)xb1.w;
        acc0 = __builtin_amdgcn_mfma_f32_16x16x32_bf16(af, b0, acc0, 0,0,0);
        acc1 = __builtin_amdgcn_mfma_f32_16x16x32_bf16(af, b1, acc1, 0,0,0);
    }
    *reinterpret_cast<f32x4*>(&red[wv][0][l16][g*4]) = acc0;
    *reinterpret_cast<f32x4*>(&red[wv][1][l16][g*4]) = acc1;
    __syncthreads();
    const int h = t >> 8, ml = (t >> 4) & 15, nl = t & 15;
    float sum = bias[n0 + nl];
#pragma unroll
    for (int w = 0; w < 8; ++w) sum += red[w][h & 1][ml][nl];
    if (t < 512) out[(h * 16 + ml) * OUT_F + n0 + nl] = sum;
}

extern "C" void kernel_launch(void* const* d_in, const int* in_sizes, int n_in,
                              void* d_out, int out_size, void* d_ws, size_t ws_size,
                              hipStream_t stream) {
    const float* x      = (const float*)d_in[0];
    const int*   qw     = (const int*)d_in[1];
    const float* scales = (const float*)d_in[2];
    const float* bias   = (const float*)d_in[3];
    float* out = (float*)d_out;

    const size_t NEED = (size_t)NSPLIT * M * OUT_F * sizeof(float);   // 4 MB
    if (ws_size >= NEED) {
        float* part = (float*)d_ws;
        qlin_gemm<<<dim3(NTILE * NSPLIT), dim3(256), 0, stream>>>(x, qw, scales, part);
        qlin_reduce<<<dim3((M * OUT_F) / (256 * 4)), dim3(256), 0, stream>>>(part, bias, out);
    } else {
        qlin_fallback<<<dim3(OUT_F / 16), dim3(512), 0, stream>>>(x, qw, scales, bias, out);
    }
}

// Round 7
// 20.572 us; speedup vs baseline: 2.5043x; 1.0256x over previous
//
#include <hip/hip_runtime.h>

typedef __bf16 bf16x8 __attribute__((ext_vector_type(8)));
typedef float f32x4 __attribute__((ext_vector_type(4)));

#define IN_F 4096
#define OUT_F 4096
#define M 32
#define BN 64           // n-rows per block
#define KC 512          // k-chunk per block
#define KSTEP 64
#define STEPS 8         // KC / KSTEP
#define NSPLIT 8        // IN_F / KC
#define NTILE 64        // OUT_F / BN

// async global->LDS, 16B/lane, LDS dest = wave-uniform base + lane*16
__device__ __forceinline__ void gload16(const void* g, void* l) {
    __builtin_amdgcn_global_load_lds(
        (const __attribute__((address_space(1))) void*)g,
        (__attribute__((address_space(3))) void*)l, 16, 0, 0);
}

template <int N>
__device__ __forceinline__ void wait_vmcnt() {
    asm volatile("s_waitcnt vmcnt(%0)" :: "n"(N) : "memory");
}

// ---- main GEMM: 512 blocks = 64 n-tiles x 8 k-splits, 256 thr = 4 waves.
// T4 structure: NO per-step barriers. Each wave stages its own W rows
// (global_load_lds, XOR-preswizzled source) into a depth-3 ring and waits
// with counted vmcnt (8 steady / 4,0 tail). X converted fp32->bf16 once in
// the prologue (single barrier). LDS 80 KB -> 2 blocks/CU.
__launch_bounds__(256, 2)
__global__ void qlin_gemm(const float* __restrict__ x,
                          const int* __restrict__ qw,
                          const float* __restrict__ scales,
                          float* __restrict__ part) {
    __shared__ int    Wb[3][BN][KSTEP];   // 3 x 16 KB ring
    __shared__ __bf16 Xs[M][KC];          // 32 KB

    const int t    = threadIdx.x;
    const int lane = t & 63;
    const int wv   = t >> 6;      // 0..3
    const int l16  = lane & 15;
    const int g4   = lane >> 4;   // 0..3
    const int xr   = l16 & 7;

    const int nt    = blockIdx.x & (NTILE - 1);
    const int split = blockIdx.x >> 6;
    const int n0    = nt * BN;
    const int k0    = split * KC;

    // per-lane persistent scales: wave's A-row, the 4 groups of this split.
    // Loaded BEFORE the prologue barrier and pinned, so no VMEM op other
    // than the W stages is in flight inside the counted-vmcnt loop.
    const int arow = n0 + wv * 16 + l16;
    const f32x4 sc = *reinterpret_cast<const f32x4*>(
        scales + arow * (IN_F / 128) + split * 4);

    f32x4 a0 = {0.f, 0.f, 0.f, 0.f};
    f32x4 a1 = {0.f, 0.f, 0.f, 0.f};

    auto stageW = [&](int buf, int s) {
        const int kk = k0 + s * KSTEP;
#pragma unroll
        for (int i = 0; i < 4; ++i) {
            const int r    = wv * 16 + i * 4 + g4;   // LDS row == tile row
            const int slot = l16 ^ (r & 7);          // involution, bit3 kept
            gload16(qw + (size_t)(n0 + r) * IN_F + kk + slot * 4,
                    &Wb[buf][wv * 16 + i * 4][0]);
        }
    };

    // ---- prologue: convert+stage X once (reg-staged, swizzled ds_write) ----
#pragma unroll
    for (int i = 0; i < 8; ++i) {
        const int r = wv * 8 + i;
        const float4 a = *reinterpret_cast<const float4*>(
            x + (size_t)r * IN_F + k0 + lane * 8);
        const float4 b = *reinterpret_cast<const float4*>(
            x + (size_t)r * IN_F + k0 + lane * 8 + 4);
        bf16x8 v;
        v[0] = (__bf16)a.x; v[1] = (__bf16)a.y; v[2] = (__bf16)a.z; v[3] = (__bf16)a.w;
        v[4] = (__bf16)b.x; v[5] = (__bf16)b.y; v[6] = (__bf16)b.z; v[7] = (__bf16)b.w;
        const int c = (lane & ~7) | ((lane & 7) ^ (r & 7));
        *reinterpret_cast<bf16x8*>(&Xs[r][c * 8]) = v;
    }
    // pin sc so its load is issued before the barrier (keeps loop vmcnt pure)
    asm volatile("" :: "v"(sc[0]), "v"(sc[1]), "v"(sc[2]), "v"(sc[3]));
    __syncthreads();            // drains vmcnt+lgkm; X now read-only, shared

    stageW(0, 0);
    stageW(1, 1);

    auto compute = [&](int buf, int s) {
#pragma unroll
        for (int q = 0; q < 2; ++q) {
            const int s0 = q * 8 + g4 * 2;
            const int4 w0 = *reinterpret_cast<const int4*>(
                &Wb[buf][wv * 16 + l16][((s0)     ^ xr) * 4]);
            const int4 w1 = *reinterpret_cast<const int4*>(
                &Wb[buf][wv * 16 + l16][((s0 + 1) ^ xr) * 4]);
            const float fs = sc[(2 * s + q) >> 2];   // static after unroll
            bf16x8 af;
            af[0] = (__bf16)((float)w0.x * fs);
            af[1] = (__bf16)((float)w0.y * fs);
            af[2] = (__bf16)((float)w0.z * fs);
            af[3] = (__bf16)((float)w0.w * fs);
            af[4] = (__bf16)((float)w1.x * fs);
            af[5] = (__bf16)((float)w1.y * fs);
            af[6] = (__bf16)((float)w1.z * fs);
            af[7] = (__bf16)((float)w1.w * fs);
            const int xc = (s * 8) | ((q * 4 + g4) ^ xr);
            const bf16x8 b0 = *reinterpret_cast<const bf16x8*>(&Xs[l16][xc * 8]);
            const bf16x8 b1 = *reinterpret_cast<const bf16x8*>(&Xs[16 + l16][xc * 8]);
            a0 = __builtin_amdgcn_mfma_f32_16x16x32_bf16(af, b0, a0, 0, 0, 0);
            a1 = __builtin_amdgcn_mfma_f32_16x16x32_bf16(af, b1, a1, 0, 0, 0);
        }
    };

    // ---- barrier-free main loop: per-wave counted vmcnt (T4) ----
#pragma unroll
    for (int s = 0; s < STEPS; ++s) {
        // ds_reads of buf (s-1)%3 must retire before stage(s+2) overwrites it
        asm volatile("s_waitcnt lgkmcnt(0)" ::: "memory");
        if (s + 2 < STEPS) stageW((s + 2) % 3, s + 2);
        if (s < STEPS - 2)       wait_vmcnt<8>();   // stages s+1,s+2 in flight
        else if (s == STEPS - 2) wait_vmcnt<4>();   // stage s+1 in flight
        else                     wait_vmcnt<0>();
        compute(s % 3, s);
    }

    // D layout (verified R3-R6): m = l16 (+16 for a1), n = n0+wv*16+g4*4+reg
    float* dst = part + (size_t)split * (M * OUT_F);
    const int nb = n0 + wv * 16 + g4 * 4;
    *reinterpret_cast<f32x4*>(dst + (size_t)l16 * OUT_F + nb)        = a0;
    *reinterpret_cast<f32x4*>(dst + (size_t)(16 + l16) * OUT_F + nb) = a1;
}

// ---- partials + bias -> out ----
__global__ __launch_bounds__(256) void qlin_reduce(const float* __restrict__ part,
                                                   const float* __restrict__ bias,
                                                   float* __restrict__ out) {
    const int i = (blockIdx.x * 256 + threadIdx.x) * 4;
    const int n = i & (OUT_F - 1);
    f32x4 s = *reinterpret_cast<const f32x4*>(bias + n);
#pragma unroll
    for (int p = 0; p < NSPLIT; ++p)
        s += *reinterpret_cast<const f32x4*>(part + (size_t)p * (M * OUT_F) + i);
    *reinterpret_cast<f32x4*>(out + i) = s;
}

// ---- fallback (round-3 validated, no ws needed) ----
__launch_bounds__(512, 2)
__global__ void qlin_fallback(const float* __restrict__ x,
                              const int* __restrict__ qw,
                              const float* __restrict__ scales,
                              const float* __restrict__ bias,
                              float* __restrict__ out) {
    __shared__ float red[8][2][16][20];
    const int t = threadIdx.x, lane = t & 63, wv = t >> 6;
    const int l16 = lane & 15, g = lane >> 4;
    const int n0 = blockIdx.x * 16, row = n0 + l16, kw0 = wv * 512;
    const int*   wp  = qw + row * IN_F + kw0 + g * 8;
    const float* xp0 = x + l16 * IN_F + kw0 + g * 8;
    const float* xp1 = x + (16 + l16) * IN_F + kw0 + g * 8;
    const int scbase = row * (IN_F / 128) + (kw0 >> 7);
    f32x4 acc0 = {0.f,0.f,0.f,0.f}, acc1 = {0.f,0.f,0.f,0.f};
#pragma unroll
    for (int s = 0; s < 16; ++s) {
        const int off = s * 32;
        const int4 w0 = *reinterpret_cast<const int4*>(wp + off);
        const int4 w1 = *reinterpret_cast<const int4*>(wp + off + 4);
        const float scv = scales[scbase + (s >> 2)];
        const float4 xa0 = *reinterpret_cast<const float4*>(xp0 + off);
        const float4 xa1 = *reinterpret_cast<const float4*>(xp0 + off + 4);
        const float4 xb0 = *reinterpret_cast<const float4*>(xp1 + off);
        const float4 xb1 = *reinterpret_cast<const float4*>(xp1 + off + 4);
        bf16x8 af, b0, b1;
        af[0]=(__bf16)((float)w0.x*scv); af[1]=(__bf16)((float)w0.y*scv);
        af[2]=(__bf16)((float)w0.z*scv); af[3]=(__bf16)((float)w0.w*scv);
        af[4]=(__bf16)((float)w1.x*scv); af[5]=(__bf16)((float)w1.y*scv);
        af[6]=(__bf16)((float)w1.z*scv); af[7]=(__bf16)((float)w1.w*scv);
        b0[0]=(__bf16)xa0.x; b0[1]=(__bf16)xa0.y; b0[2]=(__bf16)xa0.z; b0[3]=(__bf16)xa0.w;
        b0[4]=(__bf16)xa1.x; b0[5]=(__bf16)xa1.y; b0[6]=(__bf16)xa1.z; b0[7]=(__bf16)xa1.w;
        b1[0]=(__bf16)xb0.x; b1[1]=(__bf16)xb0.y; b1[2]=(__bf16)xb0.z; b1[3]=(__bf16)xb0.w;
        b1[4]=(__bf16)xb1.x; b1[5]=(__bf16)xb1.y; b1[6]=(__bf16)xb1.z; b1[7]=(__bf16)xb1.w;
        acc0 = __builtin_amdgcn_mfma_f32_16x16x32_bf16(af, b0, acc0, 0,0,0);
        acc1 = __builtin_amdgcn_mfma_f32_16x16x32_bf16(af, b1, acc1, 0,0,0);
    }
    *reinterpret_cast<f32x4*>(&red[wv][0][l16][g*4]) = acc0;
    *reinterpret_cast<f32x4*>(&red[wv][1][l16][g*4]) = acc1;
    __syncthreads();
    const int h = t >> 8, ml = (t >> 4) & 15, nl = t & 15;
    float sum = bias[n0 + nl];
#pragma unroll
    for (int w = 0; w < 8; ++w) sum += red[w][h & 1][ml][nl];
    if (t < 512) out[(h * 16 + ml) * OUT_F + n0 + nl] = sum;
}

extern "C" void kernel_launch(void* const* d_in, const int* in_sizes, int n_in,
                              void* d_out, int out_size, void* d_ws, size_t ws_size,
                              hipStream_t stream) {
    const float* x      = (const float*)d_in[0];
    const int*   qw     = (const int*)d_in[1];
    const float* scales = (const float*)d_in[2];
    const float* bias   = (const float*)d_in[3];
    float* out = (float*)d_out;

    const size_t NEED = (size_t)NSPLIT * M * OUT_F * sizeof(float);   // 4 MB
    if (ws_size >= NEED) {
        float* part = (float*)d_ws;
        qlin_gemm<<<dim3(NTILE * NSPLIT), dim3(256), 0, stream>>>(x, qw, scales, part);
        qlin_reduce<<<dim3((M * OUT_F) / (256 * 4)), dim3(256), 0, stream>>>(part, bias, out);
    } else {
        qlin_fallback<<<dim3(OUT_F / 16), dim3(512), 0, stream>>>(x, qw, scales, bias, out);
    }
}